// Round 10
// baseline (47866.641 us; speedup 1.0000x reference)
//
#include <hip/hip_runtime.h>
#include <math.h>

#define BS 128
#define L 512
#define ENC 512
#define DEC 1024
#define ATTN 512
#define EMB 256
#define VOCAB 128
#define TMAX 128
#define KCAT 1792  // EMB+ENC+DEC
#define G4 4096    // 4*DEC
#define NBLK 512   // persistent grid: 2 blocks/CU x 256 CUs
#define NGRP 64    // barrier groups (8 blocks each)

// ---- workspace layout (float offsets) ----
#define OFF_WE     0ull                       // [BS][ATTN][L]     33554432
#define OFF_WGR    33554432ull                // [G4][KCAT] d-major 7340032
#define OFF_BGR    40894464ull                // [G4] d-major          4096
#define OFF_WOUTT  40898560ull                // [DEC][VOCAB]        131072
#define OFF_WDT    41029632ull                // [DEC][ATTN]         524288
#define OFF_C      41553920ull                // [BS][DEC]           131072
#define OFF_WDEC   41684992ull                // [BS][ATTN]           65536
#define OFF_SC     41750528ull                // [BS][L]              65536
#define OFF_XCAT   41816064ull                // [BS][KCAT]          229376
#define OFF_GPART  42045440ull                // [4][BS][G4]        2097152
// end: 44142592 floats = 176.6 MB

// ---- software grid barrier state (monotonic, hierarchical, distributed flags) ----
__device__ int g_grp[NGRP * 16];   // arrival counters, 64B-strided
__device__ int g_top;
__device__ int g_flag[NGRP * 16];  // per-group generation flags, 64B-strided

// branch-free tanh: exp + Newton-refined rcp, ~3e-7 rel err
__device__ __forceinline__ float tanh_fast(float x) {
    float ax = fabsf(x);
    float e = __expf(-2.f * ax);
    float d = 1.f + e;
    float r = __builtin_amdgcn_rcpf(d);
    r = r * (2.f - d * r);
    float t = 1.f - 2.f * e * r;
    return copysignf(t, x);
}

// hierarchical monotonic grid barrier: relaxed spin on distributed flags, fence-based sync
__device__ __forceinline__ void gbar(int nb, int bid) {
    __syncthreads();
    if (threadIdx.x == 0) {
        int grp = bid >> 3;  // 8 blocks per group
        int prev = __hip_atomic_fetch_add(&g_grp[grp * 16], 1,
                                          __ATOMIC_ACQ_REL, __HIP_MEMORY_SCOPE_AGENT);
        if (prev == nb * 8 + 7) {  // last of group
            int p2 = __hip_atomic_fetch_add(&g_top, 1,
                                            __ATOMIC_ACQ_REL, __HIP_MEMORY_SCOPE_AGENT);
            if (p2 == nb * NGRP + (NGRP - 1)) {  // last overall: publish
                __threadfence();  // release fence: all prior writes visible first
                #pragma unroll
                for (int g = 0; g < NGRP; g++)
                    __hip_atomic_store(&g_flag[g * 16], nb + 1,
                                       __ATOMIC_RELAXED, __HIP_MEMORY_SCOPE_AGENT);
            }
        }
        // distributed relaxed spin: ~8 pollers per line
        while (__hip_atomic_load(&g_flag[grp * 16], __ATOMIC_RELAXED,
                                 __HIP_MEMORY_SCOPE_AGENT) <= nb) {
            __builtin_amdgcn_s_sleep(16);
        }
        __threadfence();  // acquire fence: invalidate local caches once
    }
    __syncthreads();
}

// ---------------- one-time prep: d-major W_gate concat, bias sum, W_out^T, W_dec^T ----------------
__global__ void k_prep(const float* __restrict__ W_ih, const float* __restrict__ W_hh,
                       const float* __restrict__ b_ih, const float* __restrict__ b_hh,
                       const float* __restrict__ W_out, const float* __restrict__ W_dec,
                       float* __restrict__ Wgr, float* __restrict__ bgr,
                       float* __restrict__ WoutT, float* __restrict__ WdT) {
    long i = (long)blockIdx.x * 256 + threadIdx.x;
    if (i < (long)G4 * KCAT) {
        int mp = (int)(i / KCAT), k = (int)(i % KCAT);
        int d = mp >> 2, g = mp & 3;
        int r = g * DEC + d;
        Wgr[i] = (k < EMB + ENC) ? W_ih[(long)r * (EMB + ENC) + k]
                                 : W_hh[(long)r * DEC + (k - (EMB + ENC))];
        return;
    }
    long j = i - (long)G4 * KCAT;
    if (j < G4) {
        int d = (int)(j >> 2), g = (int)(j & 3);
        int r = g * DEC + d;
        bgr[j] = b_ih[r] + b_hh[r];
        return;
    }
    long m = j - G4;
    if (m < (long)DEC * VOCAB) {
        int k = (int)(m / VOCAB), v = (int)(m % VOCAB);
        WoutT[m] = W_out[(long)v * DEC + k];
        return;
    }
    long p = m - (long)DEC * VOCAB;
    if (p < (long)DEC * ATTN) {
        int k = (int)(p / ATTN), a = (int)(p % ATTN);
        WdT[p] = W_dec[(long)a * DEC + k];
    }
}

// ---------------- one-time init: c=0, Xcat=[emb(SOS)|0|0], wdec=b_dec, barrier reset ----------------
__global__ void k_init(const float* __restrict__ emb_table, const float* __restrict__ b_dec,
                       float* __restrict__ c, float* __restrict__ Xcat,
                       float* __restrict__ wdec) {
    long i = (long)blockIdx.x * 256 + threadIdx.x;
    if (i == 0) {
        g_top = 0;
        for (int q = 0; q < NGRP * 16; q++) { g_grp[q] = 0; g_flag[q] = 0; }
    }
    if (i < BS * DEC) { c[i] = 0.f; return; }
    long j = i - BS * DEC;
    if (j < (long)BS * KCAT) {
        int cdx = (int)(j % KCAT);
        Xcat[j] = (cdx < EMB) ? emb_table[cdx] : 0.f;  // SOS = row 0
        return;
    }
    long p = j - (long)BS * KCAT;
    if (p < (long)BS * ATTN) {
        wdec[p] = b_dec[(int)(p % ATTN)];              // h0 = 0
    }
}

// ---------------- weighted_enc[b,a,l] = sum_e W_enc[a,e]*enc[b,e,l] + b_enc[a] ----------------
__global__ __launch_bounds__(256) void k_wenc(const float* __restrict__ W_enc,
                                              const float* __restrict__ b_enc,
                                              const float* __restrict__ enc_out,
                                              float* __restrict__ we) {
    __shared__ float As[16][68];
    __shared__ float Bs[16][68];
    int b = blockIdx.z;
    int a0 = blockIdx.y * 64;
    int l0 = blockIdx.x * 64;
    int t = threadIdx.x;
    int ty = t >> 4, tx = t & 15;
    float acc[4][4] = {};
    for (int e0 = 0; e0 < ENC; e0 += 16) {
        {
            int ar = t >> 2;
            int kg = (t & 3) << 2;
            float4 w4 = *(const float4*)&W_enc[(size_t)(a0 + ar) * ENC + e0 + kg];
            As[kg + 0][ar] = w4.x; As[kg + 1][ar] = w4.y; As[kg + 2][ar] = w4.z; As[kg + 3][ar] = w4.w;
            int er = t >> 4;
            int lg = (t & 15) << 2;
            float4 x4 = *(const float4*)&enc_out[((size_t)b * ENC + e0 + er) * L + l0 + lg];
            *(float4*)&Bs[er][lg] = x4;
        }
        __syncthreads();
        #pragma unroll
        for (int kk = 0; kk < 16; kk++) {
            float4 a4 = *(const float4*)&As[kk][ty * 4];
            float4 x4 = *(const float4*)&Bs[kk][tx * 4];
            float av[4] = {a4.x, a4.y, a4.z, a4.w};
            float xv[4] = {x4.x, x4.y, x4.z, x4.w};
            #pragma unroll
            for (int i = 0; i < 4; i++)
                #pragma unroll
                for (int j = 0; j < 4; j++) acc[i][j] += av[i] * xv[j];
        }
        __syncthreads();
    }
    #pragma unroll
    for (int i = 0; i < 4; i++) {
        float be = b_enc[a0 + ty * 4 + i];
        float4 o = {acc[i][0] + be, acc[i][1] + be, acc[i][2] + be, acc[i][3] + be};
        *(float4*)&we[((size_t)b * ATTN + a0 + ty * 4 + i) * L + l0 + tx * 4] = o;
    }
}

// ---------------- persistent megakernel: 128 steps x 5 phases, sw grid barrier ----------------
struct PArgs {
    const float *we, *Wgr, *bgr, *WoutT, *WdT, *v_e, *b_e, *emb, *b_out, *b_dec, *enc_out;
    float *c, *wdec, *sc, *Xcat, *gpart, *logp, *preds, *attn;
};

__global__ __launch_bounds__(256, 2) void k_persist(PArgs P) {
    __shared__ float wd[ATTN];
    __shared__ float ve[ATTN];
    __shared__ float al[L];
    __shared__ float red[256];
    __shared__ float hs[DEC];
    __shared__ float rv[128];
    __shared__ int ri[128];
    __shared__ float As[16][68];
    __shared__ float Xs[16][68];
    __shared__ float Hs2[8][256];

    int slot = blockIdx.x;
    int t = threadIdx.x;
    int nb = 0;

    for (int ts = 0; ts < TMAX; ts++) {
        // ======== Phase A: scores (128 b x 4 l-chunks of 128; 2 a-halves) ========
        {
            int b = slot >> 2;
            int l0 = (slot & 3) * 128;
            wd[t] = P.wdec[(size_t)b * ATTN + t];
            wd[t + 256] = P.wdec[(size_t)b * ATTN + t + 256];
            ve[t] = P.v_e[t];
            ve[t + 256] = P.v_e[t + 256];
            __syncthreads();
            int l = l0 + (t & 127);
            int ah = t >> 7;
            const float* p = P.we + ((size_t)b * ATTN + ah * 256) * L + l;
            float acc = 0.f;
            #pragma unroll 8
            for (int a = 0; a < 256; a++) {
                float x = p[(size_t)a * L] + wd[ah * 256 + a];
                acc += ve[ah * 256 + a] * tanh_fast(x);
            }
            if (ah == 1) red[t & 127] = acc;
            __syncthreads();
            if (ah == 0) P.sc[(size_t)b * L + l] = acc + red[t] + P.b_e[0];
        }
        gbar(nb++, slot);

        // ======== Phase B: softmax + context (128 b x 4 e-chunks of 128) ========
        {
            int b = slot >> 2, ec = slot & 3;
            float v0 = P.sc[(size_t)b * L + t], v1 = P.sc[(size_t)b * L + t + 256];
            red[t] = fmaxf(v0, v1);
            __syncthreads();
            for (int s = 128; s; s >>= 1) { if (t < s) red[t] = fmaxf(red[t], red[t + s]); __syncthreads(); }
            float m = red[0];
            __syncthreads();
            float e0 = expf(v0 - m), e1 = expf(v1 - m);
            red[t] = e0 + e1;
            __syncthreads();
            for (int s = 128; s; s >>= 1) { if (t < s) red[t] += red[t + s]; __syncthreads(); }
            float inv = 1.f / red[0];
            al[t] = e0 * inv; al[t + 256] = e1 * inv;
            __syncthreads();
            if (ec == 0) {
                float* dst = P.attn + ((size_t)b * TMAX + ts) * L;
                dst[t] = al[t]; dst[t + 256] = al[t + 256];
            }
            int w = t >> 6, lane = t & 63;
            int e = ec * 128 + w * 32 + (lane >> 1);
            int lh = (lane & 1) * 256;
            const float* ep = P.enc_out + ((size_t)b * ENC + e) * L + lh;
            float acc = 0.f;
            #pragma unroll 8
            for (int i = 0; i < 64; i++) {
                float4 x = *(const float4*)&ep[i * 4];
                float4 a4 = *(const float4*)&al[lh + i * 4];
                acc += x.x * a4.x + x.y * a4.y + x.z * a4.z + x.w * a4.w;
            }
            acc += __shfl_xor(acc, 1, 64);
            if ((lane & 1) == 0) P.Xcat[(size_t)b * KCAT + EMB + e] = acc;
        }
        gbar(nb++, slot);

        // ======== Phase C: gates partials (64 M x 2 b-halves x 4 K-splits) ========
        {
            int M0 = (slot & 63) * 64;
            int rest = slot >> 6;       // 0..7
            int b0 = (rest & 1) * 64;
            int ks = rest >> 1;         // 0..3
            int kbase = ks * 448, kend = kbase + 448;
            int ty = t >> 4, tx = t & 15;
            int r = t >> 2, kg = (t & 3) << 2;
            float acc[4][4] = {};
            float4 wreg = *(const float4*)&P.Wgr[(size_t)(M0 + r) * KCAT + kbase + kg];
            float4 xreg = *(const float4*)&P.Xcat[(size_t)(b0 + r) * KCAT + kbase + kg];
            for (int k0 = kbase; k0 < kend; k0 += 16) {
                As[kg + 0][r] = wreg.x; As[kg + 1][r] = wreg.y; As[kg + 2][r] = wreg.z; As[kg + 3][r] = wreg.w;
                Xs[kg + 0][r] = xreg.x; Xs[kg + 1][r] = xreg.y; Xs[kg + 2][r] = xreg.z; Xs[kg + 3][r] = xreg.w;
                __syncthreads();
                if (k0 + 16 < kend) {
                    wreg = *(const float4*)&P.Wgr[(size_t)(M0 + r) * KCAT + k0 + 16 + kg];
                    xreg = *(const float4*)&P.Xcat[(size_t)(b0 + r) * KCAT + k0 + 16 + kg];
                }
                #pragma unroll
                for (int kk = 0; kk < 16; kk++) {
                    float4 a4 = *(const float4*)&As[kk][ty * 4];
                    float4 x4 = *(const float4*)&Xs[kk][tx * 4];
                    float av[4] = {a4.x, a4.y, a4.z, a4.w};
                    float xv[4] = {x4.x, x4.y, x4.z, x4.w};
                    #pragma unroll
                    for (int i = 0; i < 4; i++)
                        #pragma unroll
                        for (int j = 0; j < 4; j++) acc[i][j] += av[i] * xv[j];
                }
                __syncthreads();
            }
            float* gp = P.gpart + (size_t)ks * BS * G4;
            #pragma unroll
            for (int j = 0; j < 4; j++) {
                float4 o = {acc[0][j], acc[1][j], acc[2][j], acc[3][j]};
                *(float4*)&gp[(size_t)(b0 + tx * 4 + j) * G4 + M0 + ty * 4] = o;
            }
        }
        gbar(nb++, slot);

        // ======== Phase D1: LSTM cell (128 b x 4 d-chunks of 256) ========
        {
            int b = slot >> 2, q = slot & 3;
            int d = q * 256 + t;
            const float* gp = P.gpart + (size_t)b * G4 + d * 4;
            float4 g = *(const float4*)gp;
            #pragma unroll
            for (int ks = 1; ks < 4; ks++) {
                float4 p4 = *(const float4*)(gp + (size_t)ks * BS * G4);
                g.x += p4.x; g.y += p4.y; g.z += p4.z; g.w += p4.w;
            }
            float4 bb = *(const float4*)&P.bgr[(size_t)d * 4];
            float gi = g.x + bb.x, gf = g.y + bb.y, gg = g.z + bb.z, go = g.w + bb.w;
            float fi = 1.f / (1.f + expf(-gi));
            float ff = 1.f / (1.f + expf(-gf));
            float fg = tanhf(gg);
            float fo = 1.f / (1.f + expf(-go));
            size_t ix = (size_t)b * DEC + d;
            float cn = ff * P.c[ix] + fi * fg;
            float hn = fo * tanhf(cn);
            P.c[ix] = cn;
            P.Xcat[(size_t)b * KCAT + EMB + ENC + d] = hn;
        }
        gbar(nb++, slot);

        // ======== Phase D2: logits/argmax/emb (slots 0..127) || wdec GEMM (slots 128..159) ========
        if (slot < BS) {
            int b = slot;
            const float* hsrc = P.Xcat + (size_t)b * KCAT + EMB + ENC;
            hs[t] = hsrc[t];
            hs[t + 256] = hsrc[t + 256];
            hs[t + 512] = hsrc[t + 512];
            hs[t + 768] = hsrc[t + 768];
            __syncthreads();
            int v = t & 127, kh = t >> 7;
            const float* wp = P.WoutT + (size_t)kh * 512 * VOCAB + v;
            float acc = 0.f;
            #pragma unroll 8
            for (int k = 0; k < 512; k++) acc += wp[(size_t)k * VOCAB] * hs[kh * 512 + k];
            red[t] = acc;
            __syncthreads();
            float logits = 0.f;
            if (t < 128) {
                logits = red[t] + red[t + 128] + P.b_out[t];
                rv[t] = logits; ri[t] = t;
            }
            __syncthreads();
            for (int s = 64; s; s >>= 1) {
                if (t < s) {
                    float ov = rv[t + s]; int oi = ri[t + s];
                    if (ov > rv[t] || (ov == rv[t] && oi < ri[t])) { rv[t] = ov; ri[t] = oi; }
                }
                __syncthreads();
            }
            float m = rv[0]; int am = ri[0];
            __syncthreads();
            if (t < 128) red[t] = expf(logits - m);
            __syncthreads();
            for (int s = 64; s; s >>= 1) { if (t < s && t + s < 128) red[t] += red[t + s]; __syncthreads(); }
            if (t < 128) P.logp[((size_t)b * TMAX + ts) * VOCAB + t] = logits - m - logf(red[0]);
            if (t == 0) P.preds[(size_t)b * TMAX + ts] = (float)am;
            P.Xcat[(size_t)b * KCAT + t] = P.emb[(size_t)am * EMB + t];
        } else if (slot < BS + 32) {
            // wdec[b,a] = sum_k h[b,k]*WdT[k,a] + b_dec[a]; 32 blocks: 2 a-chunks x 16 b-chunks
            int idx = slot - BS;
            int a = (idx & 1) * 256 + t;
            int b0 = (idx >> 1) * 8;
            float acc[8] = {};
            for (int kc = 0; kc < 4; kc++) {
                int bi = t >> 5;
                int kb = (t & 31) * 8;
                const float* src = P.Xcat + (size_t)(b0 + bi) * KCAT + EMB + ENC + kc * 256 + kb;
                #pragma unroll
                for (int j = 0; j < 8; j++) Hs2[bi][kb + j] = src[j];
                __syncthreads();
                const float* wdp = P.WdT + (size_t)(kc * 256) * ATTN + a;
                for (int k = 0; k < 256; k++) {
                    float wv = wdp[(size_t)k * ATTN];
                    #pragma unroll
                    for (int b8 = 0; b8 < 8; b8++) acc[b8] += Hs2[b8][k] * wv;
                }
                __syncthreads();
            }
            #pragma unroll
            for (int b8 = 0; b8 < 8; b8++)
                P.wdec[(size_t)(b0 + b8) * ATTN + a] = acc[b8] + P.b_dec[a];
        }
        gbar(nb++, slot);
    }
}

extern "C" void kernel_launch(void* const* d_in, const int* in_sizes, int n_in,
                              void* d_out, int out_size, void* d_ws, size_t ws_size,
                              hipStream_t stream) {
    const float* enc_out = (const float*)d_in[0];
    const float* W_enc   = (const float*)d_in[1];
    const float* b_enc   = (const float*)d_in[2];
    const float* W_dec   = (const float*)d_in[3];
    const float* b_dec   = (const float*)d_in[4];
    const float* v_e     = (const float*)d_in[5];
    const float* b_e     = (const float*)d_in[6];
    const float* emb     = (const float*)d_in[7];
    const float* W_ih    = (const float*)d_in[8];
    const float* W_hh    = (const float*)d_in[9];
    const float* b_ih    = (const float*)d_in[10];
    const float* b_hh    = (const float*)d_in[11];
    const float* W_out   = (const float*)d_in[12];
    const float* b_out   = (const float*)d_in[13];

    float* ws    = (float*)d_ws;
    float* we    = ws + OFF_WE;
    float* Wgr   = ws + OFF_WGR;
    float* bgr   = ws + OFF_BGR;
    float* WoutT = ws + OFF_WOUTT;
    float* WdT   = ws + OFF_WDT;
    float* c     = ws + OFF_C;
    float* wdec  = ws + OFF_WDEC;
    float* sc    = ws + OFF_SC;
    float* Xcat  = ws + OFF_XCAT;
    float* gpart = ws + OFF_GPART;

    float* logp_out  = (float*)d_out;
    float* preds_out = logp_out + (size_t)BS * TMAX * VOCAB;
    float* attn_out  = preds_out + (size_t)BS * TMAX;

    {
        long n = (long)G4 * KCAT + G4 + (long)DEC * VOCAB + (long)DEC * ATTN;
        k_prep<<<(int)((n + 255) / 256), 256, 0, stream>>>(W_ih, W_hh, b_ih, b_hh, W_out, W_dec,
                                                           Wgr, bgr, WoutT, WdT);
    }
    {
        long n = (long)BS * DEC + (long)BS * KCAT + (long)BS * ATTN;
        k_init<<<(int)((n + 255) / 256), 256, 0, stream>>>(emb, b_dec, c, Xcat, wdec);
    }
    k_wenc<<<dim3(8, 8, 128), 256, 0, stream>>>(W_enc, b_enc, enc_out, we);

    PArgs P;
    P.we = we; P.Wgr = Wgr; P.bgr = bgr; P.WoutT = WoutT; P.WdT = WdT;
    P.v_e = v_e; P.b_e = b_e; P.emb = emb; P.b_out = b_out; P.b_dec = b_dec;
    P.enc_out = enc_out;
    P.c = c; P.wdec = wdec; P.sc = sc; P.Xcat = Xcat; P.gpart = gpart;
    P.logp = logp_out; P.preds = preds_out; P.attn = attn_out;
    k_persist<<<NBLK, 256, 0, stream>>>(P);
}

// Round 11
// 25848.126 us; speedup vs baseline: 1.8518x; 1.8518x over previous
//
#include <hip/hip_runtime.h>
#include <math.h>

#define BS 128
#define L 512
#define ENC 512
#define DEC 1024
#define ATTN 512
#define EMB 256
#define VOCAB 128
#define TMAX 128
#define KCAT 1792  // EMB+ENC+DEC
#define G4 4096    // 4*DEC

// ---- workspace layout (float offsets) ----
#define OFF_WET    0ull                       // [BS][L][ATTN]     33554432
#define OFF_WGR    33554432ull                // [G4][KCAT] d-major 7340032
#define OFF_BGR    40894464ull                // [G4] d-major          4096
#define OFF_WOUTT  40898560ull                // [DEC][VOCAB]        131072
#define OFF_WDT    41029632ull                // [DEC][ATTN]         524288
#define OFF_C      41553920ull                // [BS][DEC]           131072
#define OFF_WDEC   41684992ull                // [BS][ATTN]           65536
#define OFF_SC     41750528ull                // [BS][L]              65536
#define OFF_XCAT   41816064ull                // [BS][KCAT]          229376
#define OFF_GPART  42045440ull                // [4][BS][G4]        2097152
// end: 44142592 floats = 176.6 MB

// branch-free tanh: exp + Newton-refined rcp, ~3e-7 rel err
__device__ __forceinline__ float tanh_fast(float x) {
    float ax = fabsf(x);
    float e = __expf(-2.f * ax);
    float d = 1.f + e;
    float r = __builtin_amdgcn_rcpf(d);
    r = r * (2.f - d * r);
    float t = 1.f - 2.f * e * r;
    return copysignf(t, x);
}

// ---------------- one-time prep: d-major W_gate concat, bias sum, W_out^T, W_dec^T ----------------
__global__ void k_prep(const float* __restrict__ W_ih, const float* __restrict__ W_hh,
                       const float* __restrict__ b_ih, const float* __restrict__ b_hh,
                       const float* __restrict__ W_out, const float* __restrict__ W_dec,
                       float* __restrict__ Wgr, float* __restrict__ bgr,
                       float* __restrict__ WoutT, float* __restrict__ WdT) {
    long i = (long)blockIdx.x * 256 + threadIdx.x;
    if (i < (long)G4 * KCAT) {
        int mp = (int)(i / KCAT), k = (int)(i % KCAT);
        int d = mp >> 2, g = mp & 3;
        int r = g * DEC + d;
        Wgr[i] = (k < EMB + ENC) ? W_ih[(long)r * (EMB + ENC) + k]
                                 : W_hh[(long)r * DEC + (k - (EMB + ENC))];
        return;
    }
    long j = i - (long)G4 * KCAT;
    if (j < G4) {
        int d = (int)(j >> 2), g = (int)(j & 3);
        int r = g * DEC + d;
        bgr[j] = b_ih[r] + b_hh[r];
        return;
    }
    long m = j - G4;
    if (m < (long)DEC * VOCAB) {
        int k = (int)(m / VOCAB), v = (int)(m % VOCAB);
        WoutT[m] = W_out[(long)v * DEC + k];
        return;
    }
    long p = m - (long)DEC * VOCAB;
    if (p < (long)DEC * ATTN) {
        int k = (int)(p / ATTN), a = (int)(p % ATTN);
        WdT[p] = W_dec[(long)a * DEC + k];
    }
}

// ---------------- one-time init: c=0, Xcat=[emb(SOS)|0|0], wdec=b_dec ----------------
__global__ void k_init(const float* __restrict__ emb_table, const float* __restrict__ b_dec,
                       float* __restrict__ c, float* __restrict__ Xcat,
                       float* __restrict__ wdec) {
    long i = (long)blockIdx.x * 256 + threadIdx.x;
    if (i < BS * DEC) { c[i] = 0.f; return; }
    long j = i - BS * DEC;
    if (j < (long)BS * KCAT) {
        int cdx = (int)(j % KCAT);
        Xcat[j] = (cdx < EMB) ? emb_table[cdx] : 0.f;  // SOS = row 0
        return;
    }
    long p = j - (long)BS * KCAT;
    if (p < (long)BS * ATTN) {
        wdec[p] = b_dec[(int)(p % ATTN)];              // h0 = 0
    }
}

// ---------------- weighted_enc TRANSPOSED: weT[b,l,a] = sum_e W_enc[a,e]*enc[b,e,l] + b_enc[a] ----------------
__global__ __launch_bounds__(256) void k_wenc(const float* __restrict__ W_enc,
                                              const float* __restrict__ b_enc,
                                              const float* __restrict__ enc_out,
                                              float* __restrict__ weT) {
    __shared__ float As[16][68];
    __shared__ float Bs[16][68];
    int b = blockIdx.z;
    int a0 = blockIdx.y * 64;
    int l0 = blockIdx.x * 64;
    int t = threadIdx.x;
    int ty = t >> 4, tx = t & 15;
    float acc[4][4] = {};
    for (int e0 = 0; e0 < ENC; e0 += 16) {
        {
            int ar = t >> 2;
            int kg = (t & 3) << 2;
            float4 w4 = *(const float4*)&W_enc[(size_t)(a0 + ar) * ENC + e0 + kg];
            As[kg + 0][ar] = w4.x; As[kg + 1][ar] = w4.y; As[kg + 2][ar] = w4.z; As[kg + 3][ar] = w4.w;
            int er = t >> 4;
            int lg = (t & 15) << 2;
            float4 x4 = *(const float4*)&enc_out[((size_t)b * ENC + e0 + er) * L + l0 + lg];
            *(float4*)&Bs[er][lg] = x4;
        }
        __syncthreads();
        #pragma unroll
        for (int kk = 0; kk < 16; kk++) {
            float4 a4 = *(const float4*)&As[kk][ty * 4];
            float4 x4 = *(const float4*)&Bs[kk][tx * 4];
            float av[4] = {a4.x, a4.y, a4.z, a4.w};
            float xv[4] = {x4.x, x4.y, x4.z, x4.w};
            #pragma unroll
            for (int i = 0; i < 4; i++)
                #pragma unroll
                for (int j = 0; j < 4; j++) acc[i][j] += av[i] * xv[j];
        }
        __syncthreads();
    }
    float be0 = b_enc[a0 + ty * 4 + 0];
    float be1 = b_enc[a0 + ty * 4 + 1];
    float be2 = b_enc[a0 + ty * 4 + 2];
    float be3 = b_enc[a0 + ty * 4 + 3];
    #pragma unroll
    for (int j = 0; j < 4; j++) {
        int l = l0 + tx * 4 + j;
        float4 o = {acc[0][j] + be0, acc[1][j] + be1, acc[2][j] + be2, acc[3][j] + be3};
        *(float4*)&weT[((size_t)b * L + l) * ATTN + a0 + ty * 4] = o;
    }
}

// ---------------- scores[b,l] = sum_a v_e[a]*tanh(weT[b,l,a]+wdec[b,a]) + b_e ----------------
// grid 1024 = 128 b x 8 l-chunks of 64; wave per row, fully-coalesced 1KB loads
__global__ __launch_bounds__(256) void k_scores(const float* __restrict__ weT,
                                                const float* __restrict__ wdec,
                                                const float* __restrict__ v_e,
                                                const float* __restrict__ b_e,
                                                float* __restrict__ scores) {
    __shared__ float wd[ATTN];
    __shared__ float ve[ATTN];
    int b = blockIdx.x >> 3;
    int lc = blockIdx.x & 7;
    int t = threadIdx.x;
    wd[t] = wdec[(size_t)b * ATTN + t];
    wd[t + 256] = wdec[(size_t)b * ATTN + t + 256];
    ve[t] = v_e[t];
    ve[t + 256] = v_e[t + 256];
    __syncthreads();
    int w = t >> 6, lane = t & 63;
    int a0 = lane * 4, a1 = 256 + lane * 4;
    float be = b_e[0];
    #pragma unroll 4
    for (int i = 0; i < 16; i++) {
        int l = lc * 64 + w * 16 + i;
        const float* row = weT + ((size_t)b * L + l) * ATTN;
        float4 x0 = *(const float4*)&row[a0];
        float4 x1 = *(const float4*)&row[a1];
        float acc = ve[a0 + 0] * tanh_fast(x0.x + wd[a0 + 0])
                  + ve[a0 + 1] * tanh_fast(x0.y + wd[a0 + 1])
                  + ve[a0 + 2] * tanh_fast(x0.z + wd[a0 + 2])
                  + ve[a0 + 3] * tanh_fast(x0.w + wd[a0 + 3])
                  + ve[a1 + 0] * tanh_fast(x1.x + wd[a1 + 0])
                  + ve[a1 + 1] * tanh_fast(x1.y + wd[a1 + 1])
                  + ve[a1 + 2] * tanh_fast(x1.z + wd[a1 + 2])
                  + ve[a1 + 3] * tanh_fast(x1.w + wd[a1 + 3]);
        #pragma unroll
        for (int s = 32; s; s >>= 1) acc += __shfl_xor(acc, s, 64);
        if (lane == 0) scores[(size_t)b * L + l] = acc + be;
    }
}

// ---------------- fused softmax + context; wave-per-e-row coalesced ----------------
// grid 2048 = 128 b x 16 e-chunks of 32
__global__ __launch_bounds__(256) void k_smctx(const float* __restrict__ scores,
                                               const float* __restrict__ enc_out,
                                               float* __restrict__ attn_out,
                                               float* __restrict__ Xcat, int t_step) {
    __shared__ float al[L];
    __shared__ float red[256];
    int b = blockIdx.x >> 4, ec = blockIdx.x & 15;
    int t = threadIdx.x;
    float v0 = scores[(size_t)b * L + t], v1 = scores[(size_t)b * L + t + 256];
    red[t] = fmaxf(v0, v1);
    __syncthreads();
    for (int s = 128; s; s >>= 1) { if (t < s) red[t] = fmaxf(red[t], red[t + s]); __syncthreads(); }
    float m = red[0];
    __syncthreads();
    float e0 = expf(v0 - m), e1 = expf(v1 - m);
    red[t] = e0 + e1;
    __syncthreads();
    for (int s = 128; s; s >>= 1) { if (t < s) red[t] += red[t + s]; __syncthreads(); }
    float inv = 1.f / red[0];
    al[t] = e0 * inv; al[t + 256] = e1 * inv;
    __syncthreads();
    if (ec == 0) {
        float* dst = attn_out + ((size_t)b * TMAX + t_step) * L;
        dst[t] = al[t]; dst[t + 256] = al[t + 256];
    }
    // context: wave per e-row, two 1KB contiguous loads
    int w = t >> 6, lane = t & 63;
    int l0 = lane * 4, l1 = 256 + lane * 4;
    #pragma unroll 2
    for (int i = 0; i < 8; i++) {
        int e = ec * 32 + w * 8 + i;
        const float* row = enc_out + ((size_t)b * ENC + e) * L;
        float4 x0 = *(const float4*)&row[l0];
        float4 x1 = *(const float4*)&row[l1];
        float4 a0 = *(const float4*)&al[l0];
        float4 a1 = *(const float4*)&al[l1];
        float acc = x0.x * a0.x + x0.y * a0.y + x0.z * a0.z + x0.w * a0.w
                  + x1.x * a1.x + x1.y * a1.y + x1.z * a1.z + x1.w * a1.w;
        #pragma unroll
        for (int s = 32; s; s >>= 1) acc += __shfl_xor(acc, s, 64);
        if (lane == 0) Xcat[(size_t)b * KCAT + EMB + e] = acc;
    }
}

// ---------------- gates GEMM partials, K-split x4, b-split x2, reg-prefetched ----------------
// grid (64, 2, 4): 64 m'-rows x 64 b x 448 K per block -> gates_part[ks][b][m']
__global__ __launch_bounds__(256) void k_gates(const float* __restrict__ Wgr,
                                               const float* __restrict__ Xcat,
                                               float* __restrict__ gates_part) {
    __shared__ float As[16][68];  // [k][m'] 64 rows
    __shared__ float Xs[16][68];  // [k][b]  64 cols
    int M0 = blockIdx.x * 64;
    int b0 = blockIdx.y * 64;
    int ks = blockIdx.z;
    int kbase = ks * 448, kend = kbase + 448;
    int t = threadIdx.x, ty = t >> 4, tx = t & 15;
    int r = t >> 2, kg = (t & 3) << 2;
    float acc[4][4] = {};
    float4 wreg = *(const float4*)&Wgr[(size_t)(M0 + r) * KCAT + kbase + kg];
    float4 xreg = *(const float4*)&Xcat[(size_t)(b0 + r) * KCAT + kbase + kg];
    for (int k0 = kbase; k0 < kend; k0 += 16) {
        As[kg + 0][r] = wreg.x; As[kg + 1][r] = wreg.y; As[kg + 2][r] = wreg.z; As[kg + 3][r] = wreg.w;
        Xs[kg + 0][r] = xreg.x; Xs[kg + 1][r] = xreg.y; Xs[kg + 2][r] = xreg.z; Xs[kg + 3][r] = xreg.w;
        __syncthreads();
        if (k0 + 16 < kend) {
            wreg = *(const float4*)&Wgr[(size_t)(M0 + r) * KCAT + k0 + 16 + kg];
            xreg = *(const float4*)&Xcat[(size_t)(b0 + r) * KCAT + k0 + 16 + kg];
        }
        #pragma unroll
        for (int kk = 0; kk < 16; kk++) {
            float4 a4 = *(const float4*)&As[kk][ty * 4];
            float4 x4 = *(const float4*)&Xs[kk][tx * 4];
            float av[4] = {a4.x, a4.y, a4.z, a4.w};
            float xv[4] = {x4.x, x4.y, x4.z, x4.w};
            #pragma unroll
            for (int i = 0; i < 4; i++)
                #pragma unroll
                for (int j = 0; j < 4; j++) acc[i][j] += av[i] * xv[j];
        }
        __syncthreads();
    }
    float* gp = gates_part + (size_t)ks * BS * G4;
    #pragma unroll
    for (int j = 0; j < 4; j++) {
        float4 o = {acc[0][j], acc[1][j], acc[2][j], acc[3][j]};
        *(float4*)&gp[(size_t)(b0 + tx * 4 + j) * G4 + M0 + ty * 4] = o;
    }
}

// ---------------- cell (sum partials + activations) + logits + argmax + emb + wdec ----------------
__global__ __launch_bounds__(256) void k_out_cell(const float* __restrict__ gates_part,
                                                  const float* __restrict__ bgr,
                                                  const float* __restrict__ WoutT,
                                                  const float* __restrict__ b_out,
                                                  const float* __restrict__ emb_table,
                                                  const float* __restrict__ WdT,
                                                  const float* __restrict__ b_dec,
                                                  float* __restrict__ c,
                                                  float* __restrict__ logp_out,
                                                  float* __restrict__ preds_out,
                                                  float* __restrict__ Xcat,
                                                  float* __restrict__ wdec, int t_step) {
    __shared__ float hs[DEC];
    __shared__ float red[256];
    __shared__ float rv[128];
    __shared__ int ri[128];
    int b = blockIdx.x;
    int t = threadIdx.x;
    #pragma unroll
    for (int q = 0; q < 4; q++) {
        int d = q * 256 + t;
        const float* gp = gates_part + (size_t)b * G4 + d * 4;
        float4 g = *(const float4*)gp;
        #pragma unroll
        for (int ks = 1; ks < 4; ks++) {
            float4 p = *(const float4*)(gp + (size_t)ks * BS * G4);
            g.x += p.x; g.y += p.y; g.z += p.z; g.w += p.w;
        }
        float4 bb = *(const float4*)&bgr[(size_t)d * 4];
        float gi = g.x + bb.x, gf = g.y + bb.y, gg = g.z + bb.z, go = g.w + bb.w;
        float fi = 1.f / (1.f + expf(-gi));
        float ff = 1.f / (1.f + expf(-gf));
        float fg = tanhf(gg);
        float fo = 1.f / (1.f + expf(-go));
        size_t ix = (size_t)b * DEC + d;
        float cn = ff * c[ix] + fi * fg;
        float hn = fo * tanhf(cn);
        c[ix] = cn;
        hs[d] = hn;
        Xcat[(size_t)b * KCAT + EMB + ENC + d] = hn;
    }
    __syncthreads();
    int v = t & 127, kh = t >> 7;
    const float* wp = WoutT + (size_t)kh * 512 * VOCAB + v;
    float acc = 0.f;
    #pragma unroll 8
    for (int k = 0; k < 512; k++) acc += wp[(size_t)k * VOCAB] * hs[kh * 512 + k];
    red[t] = acc;
    __syncthreads();
    float logits = 0.f;
    if (t < 128) {
        logits = red[t] + red[t + 128] + b_out[t];
        rv[t] = logits; ri[t] = t;
    }
    __syncthreads();
    for (int s = 64; s; s >>= 1) {
        if (t < s) {
            float ov = rv[t + s]; int oi = ri[t + s];
            if (ov > rv[t] || (ov == rv[t] && oi < ri[t])) { rv[t] = ov; ri[t] = oi; }
        }
        __syncthreads();
    }
    float m = rv[0]; int am = ri[0];
    __syncthreads();
    if (t < 128) red[t] = expf(logits - m);
    __syncthreads();
    for (int s = 64; s; s >>= 1) { if (t < s && t + s < 128) red[t] += red[t + s]; __syncthreads(); }
    if (t < 128) logp_out[((size_t)b * TMAX + t_step) * VOCAB + t] = logits - m - logf(red[0]);
    if (t == 0) preds_out[(size_t)b * TMAX + t_step] = (float)am;
    Xcat[(size_t)b * KCAT + t] = emb_table[(size_t)am * EMB + t];
    #pragma unroll
    for (int a2 = 0; a2 < 2; a2++) {
        int a = t + a2 * 256;
        const float* wdp = WdT + a;
        float s = 0.f;
        #pragma unroll 8
        for (int k = 0; k < DEC; k++) s += wdp[(size_t)k * ATTN] * hs[k];
        wdec[(size_t)b * ATTN + a] = s + b_dec[a];
    }
}

extern "C" void kernel_launch(void* const* d_in, const int* in_sizes, int n_in,
                              void* d_out, int out_size, void* d_ws, size_t ws_size,
                              hipStream_t stream) {
    const float* enc_out = (const float*)d_in[0];
    const float* W_enc   = (const float*)d_in[1];
    const float* b_enc   = (const float*)d_in[2];
    const float* W_dec   = (const float*)d_in[3];
    const float* b_dec   = (const float*)d_in[4];
    const float* v_e     = (const float*)d_in[5];
    const float* b_e     = (const float*)d_in[6];
    const float* emb     = (const float*)d_in[7];
    const float* W_ih    = (const float*)d_in[8];
    const float* W_hh    = (const float*)d_in[9];
    const float* b_ih    = (const float*)d_in[10];
    const float* b_hh    = (const float*)d_in[11];
    const float* W_out   = (const float*)d_in[12];
    const float* b_out   = (const float*)d_in[13];

    float* ws    = (float*)d_ws;
    float* weT   = ws + OFF_WET;
    float* Wgr   = ws + OFF_WGR;
    float* bgr   = ws + OFF_BGR;
    float* WoutT = ws + OFF_WOUTT;
    float* WdT   = ws + OFF_WDT;
    float* c     = ws + OFF_C;
    float* wdec  = ws + OFF_WDEC;
    float* sc    = ws + OFF_SC;
    float* Xcat  = ws + OFF_XCAT;
    float* gpart = ws + OFF_GPART;

    float* logp_out  = (float*)d_out;
    float* preds_out = logp_out + (size_t)BS * TMAX * VOCAB;
    float* attn_out  = preds_out + (size_t)BS * TMAX;

    {
        long n = (long)G4 * KCAT + G4 + (long)DEC * VOCAB + (long)DEC * ATTN;
        k_prep<<<(int)((n + 255) / 256), 256, 0, stream>>>(W_ih, W_hh, b_ih, b_hh, W_out, W_dec,
                                                           Wgr, bgr, WoutT, WdT);
    }
    {
        long n = (long)BS * DEC + (long)BS * KCAT + (long)BS * ATTN;
        k_init<<<(int)((n + 255) / 256), 256, 0, stream>>>(emb, b_dec, c, Xcat, wdec);
    }
    k_wenc<<<dim3(8, 8, 128), 256, 0, stream>>>(W_enc, b_enc, enc_out, weT);

    for (int t = 0; t < TMAX; t++) {
        k_scores<<<1024, 256, 0, stream>>>(weT, wdec, v_e, b_e, sc);
        k_smctx<<<2048, 256, 0, stream>>>(sc, enc_out, attn_out, Xcat, t);
        k_gates<<<dim3(64, 2, 4), 256, 0, stream>>>(Wgr, Xcat, gpart);
        k_out_cell<<<128, 256, 0, stream>>>(gpart, bgr, WoutT, b_out, emb, WdT, b_dec,
                                            c, logp_out, preds_out, Xcat, wdec, t);
    }
}

// Round 13
// 21276.701 us; speedup vs baseline: 2.2497x; 1.2149x over previous
//
#include <hip/hip_runtime.h>
#include <math.h>

#define BS 128
#define L 512
#define ENC 512
#define DEC 1024
#define ATTN 512
#define EMB 256
#define VOCAB 128
#define TMAX 128
#define KCAT 1792  // EMB+ENC+DEC
#define G4 4096    // 4*DEC

// ---- workspace layout (float offsets) ---- (identical footprint to proven rounds)
#define OFF_WET    0ull                       // [BS][L][ATTN]     33554432
#define OFF_WGR    33554432ull                // [G4][KCAT] d-major 7340032
#define OFF_BGR    40894464ull                // [G4] d-major          4096
#define OFF_WOUTT  40898560ull                // [DEC][VOCAB]        131072
#define OFF_WDT    41029632ull                // [DEC][ATTN]         524288
#define OFF_C      41553920ull                // [BS][DEC]           131072
#define OFF_WDEC   41684992ull                // [BS][ATTN]           65536
#define OFF_SC     41750528ull                // [BS][L]  (unused)    65536
#define OFF_XCAT   41816064ull                // [BS][KCAT]          229376
#define OFF_GPART  42045440ull                // [4][BS][G4]        2097152
// end: 44142592 floats = 176.6 MB (proven size)

// branch-free tanh: exp + Newton-refined rcp, ~3e-7 rel err
__device__ __forceinline__ float tanh_fast(float x) {
    float ax = fabsf(x);
    float e = __expf(-2.f * ax);
    float d = 1.f + e;
    float r = __builtin_amdgcn_rcpf(d);
    r = r * (2.f - d * r);
    float t = 1.f - 2.f * e * r;
    return copysignf(t, x);
}

// ---------------- one-time prep: d-major W_gate concat, bias sum, W_out^T, W_dec^T ----------------
__global__ void k_prep(const float* __restrict__ W_ih, const float* __restrict__ W_hh,
                       const float* __restrict__ b_ih, const float* __restrict__ b_hh,
                       const float* __restrict__ W_out, const float* __restrict__ W_dec,
                       float* __restrict__ Wgr, float* __restrict__ bgr,
                       float* __restrict__ WoutT, float* __restrict__ WdT) {
    long i = (long)blockIdx.x * 256 + threadIdx.x;
    if (i < (long)G4 * KCAT) {
        int mp = (int)(i / KCAT), k = (int)(i % KCAT);
        int d = mp >> 2, g = mp & 3;
        int r = g * DEC + d;
        Wgr[i] = (k < EMB + ENC) ? W_ih[(long)r * (EMB + ENC) + k]
                                 : W_hh[(long)r * DEC + (k - (EMB + ENC))];
        return;
    }
    long j = i - (long)G4 * KCAT;
    if (j < G4) {
        int d = (int)(j >> 2), g = (int)(j & 3);
        int r = g * DEC + d;
        bgr[j] = b_ih[r] + b_hh[r];
        return;
    }
    long m = j - G4;
    if (m < (long)DEC * VOCAB) {
        int k = (int)(m / VOCAB), v = (int)(m % VOCAB);
        WoutT[m] = W_out[(long)v * DEC + k];
        return;
    }
    long p = m - (long)DEC * VOCAB;
    if (p < (long)DEC * ATTN) {
        int k = (int)(p / ATTN), a = (int)(p % ATTN);
        WdT[p] = W_dec[(long)a * DEC + k];
    }
}

// ---------------- one-time init: c=0, Xcat=[emb(SOS)|0|0], wdec=b_dec ----------------
__global__ void k_init(const float* __restrict__ emb_table, const float* __restrict__ b_dec,
                       float* __restrict__ c, float* __restrict__ Xcat,
                       float* __restrict__ wdec) {
    long i = (long)blockIdx.x * 256 + threadIdx.x;
    if (i < BS * DEC) { c[i] = 0.f; return; }
    long j = i - BS * DEC;
    if (j < (long)BS * KCAT) {
        int cdx = (int)(j % KCAT);
        Xcat[j] = (cdx < EMB) ? emb_table[cdx] : 0.f;  // SOS = row 0
        return;
    }
    long p = j - (long)BS * KCAT;
    if (p < (long)BS * ATTN) {
        wdec[p] = b_dec[(int)(p % ATTN)];              // h0 = 0
    }
}

// ---------------- weighted_enc TRANSPOSED f32: weT[b,l,a] ----------------
__global__ __launch_bounds__(256) void k_wenc(const float* __restrict__ W_enc,
                                              const float* __restrict__ b_enc,
                                              const float* __restrict__ enc_out,
                                              float* __restrict__ weT) {
    __shared__ float As[16][68];
    __shared__ float Bs[16][68];
    int b = blockIdx.z;
    int a0 = blockIdx.y * 64;
    int l0 = blockIdx.x * 64;
    int t = threadIdx.x;
    int ty = t >> 4, tx = t & 15;
    float acc[4][4] = {};
    for (int e0 = 0; e0 < ENC; e0 += 16) {
        {
            int ar = t >> 2;
            int kg = (t & 3) << 2;
            float4 w4 = *(const float4*)&W_enc[(size_t)(a0 + ar) * ENC + e0 + kg];
            As[kg + 0][ar] = w4.x; As[kg + 1][ar] = w4.y; As[kg + 2][ar] = w4.z; As[kg + 3][ar] = w4.w;
            int er = t >> 4;
            int lg = (t & 15) << 2;
            float4 x4 = *(const float4*)&enc_out[((size_t)b * ENC + e0 + er) * L + l0 + lg];
            *(float4*)&Bs[er][lg] = x4;
        }
        __syncthreads();
        #pragma unroll
        for (int kk = 0; kk < 16; kk++) {
            float4 a4 = *(const float4*)&As[kk][ty * 4];
            float4 x4 = *(const float4*)&Bs[kk][tx * 4];
            float av[4] = {a4.x, a4.y, a4.z, a4.w};
            float xv[4] = {x4.x, x4.y, x4.z, x4.w};
            #pragma unroll
            for (int i = 0; i < 4; i++)
                #pragma unroll
                for (int j = 0; j < 4; j++) acc[i][j] += av[i] * xv[j];
        }
        __syncthreads();
    }
    float be0 = b_enc[a0 + ty * 4 + 0];
    float be1 = b_enc[a0 + ty * 4 + 1];
    float be2 = b_enc[a0 + ty * 4 + 2];
    float be3 = b_enc[a0 + ty * 4 + 3];
    #pragma unroll
    for (int j = 0; j < 4; j++) {
        int l = l0 + tx * 4 + j;
        float4 o = {acc[0][j] + be0, acc[1][j] + be1, acc[2][j] + be2, acc[3][j] + be3};
        *(float4*)&weT[((size_t)b * L + l) * ATTN + a0 + ty * 4] = o;
    }
}

// ---------------- fused attention: scores + softmax + context, one block per b ----------------
// 512 threads: thread t = row l (scores), then e (context); softmax in LDS
__global__ __launch_bounds__(512) void k_attn(const float* __restrict__ weT,
                                              const float* __restrict__ wdec,
                                              const float* __restrict__ v_e,
                                              const float* __restrict__ b_e,
                                              const float* __restrict__ enc_out,
                                              float* __restrict__ attn_out,
                                              float* __restrict__ Xcat, int t_step) {
    __shared__ float wd[ATTN];
    __shared__ float ve[ATTN];
    __shared__ float al[L];
    __shared__ float red[512];
    int b = blockIdx.x;
    int t = threadIdx.x;
    wd[t] = wdec[(size_t)b * ATTN + t];
    ve[t] = v_e[t];
    __syncthreads();
    // scores: thread t handles row l = t (contiguous 2KB read)
    const float* row = weT + ((size_t)b * L + t) * ATTN;
    float acc = 0.f;
    #pragma unroll 8
    for (int a4 = 0; a4 < ATTN; a4 += 4) {
        float4 x = *(const float4*)&row[a4];
        acc += ve[a4 + 0] * tanh_fast(x.x + wd[a4 + 0]);
        acc += ve[a4 + 1] * tanh_fast(x.y + wd[a4 + 1]);
        acc += ve[a4 + 2] * tanh_fast(x.z + wd[a4 + 2]);
        acc += ve[a4 + 3] * tanh_fast(x.w + wd[a4 + 3]);
    }
    float sc = acc + b_e[0];
    // softmax over 512
    red[t] = sc;
    __syncthreads();
    for (int s = 256; s; s >>= 1) { if (t < s) red[t] = fmaxf(red[t], red[t + s]); __syncthreads(); }
    float m = red[0];
    __syncthreads();
    float e = expf(sc - m);
    red[t] = e;
    __syncthreads();
    for (int s = 256; s; s >>= 1) { if (t < s) red[t] += red[t + s]; __syncthreads(); }
    float inv = 1.f / red[0];
    al[t] = e * inv;
    __syncthreads();
    attn_out[((size_t)b * TMAX + t_step) * L + t] = al[t];
    // context: thread t = channel e (contiguous 2KB read of enc row)
    const float* erow = enc_out + ((size_t)b * ENC + t) * L;
    float cacc = 0.f;
    #pragma unroll 8
    for (int l4 = 0; l4 < L; l4 += 4) {
        float4 x = *(const float4*)&erow[l4];
        float4 a4 = *(const float4*)&al[l4];
        cacc += x.x * a4.x + x.y * a4.y + x.z * a4.z + x.w * a4.w;
    }
    Xcat[(size_t)b * KCAT + EMB + t] = cacc;
}

// ---------------- gates GEMM partials, K-split x4, b-split x2, reg-prefetched ----------------
__global__ __launch_bounds__(256) void k_gates(const float* __restrict__ Wgr,
                                               const float* __restrict__ Xcat,
                                               float* __restrict__ gates_part) {
    __shared__ float As[16][68];
    __shared__ float Xs[16][68];
    int M0 = blockIdx.x * 64;
    int b0 = blockIdx.y * 64;
    int ks = blockIdx.z;
    int kbase = ks * 448, kend = kbase + 448;
    int t = threadIdx.x, ty = t >> 4, tx = t & 15;
    int r = t >> 2, kg = (t & 3) << 2;
    float acc[4][4] = {};
    float4 wreg = *(const float4*)&Wgr[(size_t)(M0 + r) * KCAT + kbase + kg];
    float4 xreg = *(const float4*)&Xcat[(size_t)(b0 + r) * KCAT + kbase + kg];
    for (int k0 = kbase; k0 < kend; k0 += 16) {
        As[kg + 0][r] = wreg.x; As[kg + 1][r] = wreg.y; As[kg + 2][r] = wreg.z; As[kg + 3][r] = wreg.w;
        Xs[kg + 0][r] = xreg.x; Xs[kg + 1][r] = xreg.y; Xs[kg + 2][r] = xreg.z; Xs[kg + 3][r] = xreg.w;
        __syncthreads();
        if (k0 + 16 < kend) {
            wreg = *(const float4*)&Wgr[(size_t)(M0 + r) * KCAT + k0 + 16 + kg];
            xreg = *(const float4*)&Xcat[(size_t)(b0 + r) * KCAT + k0 + 16 + kg];
        }
        #pragma unroll
        for (int kk = 0; kk < 16; kk++) {
            float4 a4 = *(const float4*)&As[kk][ty * 4];
            float4 x4 = *(const float4*)&Xs[kk][tx * 4];
            float av[4] = {a4.x, a4.y, a4.z, a4.w};
            float xv[4] = {x4.x, x4.y, x4.z, x4.w};
            #pragma unroll
            for (int i = 0; i < 4; i++)
                #pragma unroll
                for (int j = 0; j < 4; j++) acc[i][j] += av[i] * xv[j];
        }
        __syncthreads();
    }
    float* gp = gates_part + (size_t)ks * BS * G4;
    #pragma unroll
    for (int j = 0; j < 4; j++) {
        float4 o = {acc[0][j], acc[1][j], acc[2][j], acc[3][j]};
        *(float4*)&gp[(size_t)(b0 + tx * 4 + j) * G4 + M0 + ty * 4] = o;
    }
}

// ---------------- cell + logits(4-way K) + argmax + emb + wdec; 512 threads ----------------
__global__ __launch_bounds__(512) void k_out_cell(const float* __restrict__ gates_part,
                                                  const float* __restrict__ bgr,
                                                  const float* __restrict__ WoutT,
                                                  const float* __restrict__ b_out,
                                                  const float* __restrict__ emb_table,
                                                  const float* __restrict__ WdT,
                                                  const float* __restrict__ b_dec,
                                                  float* __restrict__ c,
                                                  float* __restrict__ logp_out,
                                                  float* __restrict__ preds_out,
                                                  float* __restrict__ Xcat,
                                                  float* __restrict__ wdec, int t_step) {
    __shared__ float hs[DEC];
    __shared__ float red[512];
    __shared__ float rv[128];
    __shared__ int ri[128];
    int b = blockIdx.x;
    int t = threadIdx.x;
    #pragma unroll
    for (int q = 0; q < 2; q++) {
        int d = q * 512 + t;
        const float* gp = gates_part + (size_t)b * G4 + d * 4;
        float4 g = *(const float4*)gp;
        #pragma unroll
        for (int ks = 1; ks < 4; ks++) {
            float4 p = *(const float4*)(gp + (size_t)ks * BS * G4);
            g.x += p.x; g.y += p.y; g.z += p.z; g.w += p.w;
        }
        float4 bb = *(const float4*)&bgr[(size_t)d * 4];
        float gi = g.x + bb.x, gf = g.y + bb.y, gg = g.z + bb.z, go = g.w + bb.w;
        float fi = 1.f / (1.f + expf(-gi));
        float ff = 1.f / (1.f + expf(-gf));
        float fg = tanhf(gg);
        float fo = 1.f / (1.f + expf(-go));
        size_t ix = (size_t)b * DEC + d;
        float cn = ff * c[ix] + fi * fg;
        float hn = fo * tanhf(cn);
        c[ix] = cn;
        hs[d] = hn;
        Xcat[(size_t)b * KCAT + EMB + ENC + d] = hn;
    }
    __syncthreads();
    // logits: 4-way K split (span 256)
    int v = t & 127, kh = t >> 7;
    const float* wp = WoutT + (size_t)kh * 256 * VOCAB + v;
    float acc = 0.f;
    #pragma unroll 8
    for (int k = 0; k < 256; k++) acc += wp[(size_t)k * VOCAB] * hs[kh * 256 + k];
    red[t] = acc;
    __syncthreads();
    float logits = 0.f;
    if (t < 128) {
        logits = ((red[t] + red[t + 128]) + (red[t + 256] + red[t + 384])) + b_out[t];
        rv[t] = logits; ri[t] = t;
    }
    __syncthreads();
    for (int s = 64; s; s >>= 1) {
        if (t < s) {
            float ov = rv[t + s]; int oi = ri[t + s];
            if (ov > rv[t] || (ov == rv[t] && oi < ri[t])) { rv[t] = ov; ri[t] = oi; }
        }
        __syncthreads();
    }
    float m = rv[0]; int am = ri[0];
    __syncthreads();
    if (t < 128) red[t] = expf(logits - m);
    __syncthreads();
    for (int s = 64; s; s >>= 1) { if (t < s && t + s < 128) red[t] += red[t + s]; __syncthreads(); }
    if (t < 128) logp_out[((size_t)b * TMAX + t_step) * VOCAB + t] = logits - m - logf(red[0]);
    if (t == 0) preds_out[(size_t)b * TMAX + t_step] = (float)am;
    if (t < 256) Xcat[(size_t)b * KCAT + t] = emb_table[(size_t)am * EMB + t];
    // wdec: one a per thread, k-ascending
    {
        const float* wdp = WdT + t;
        float s = 0.f;
        #pragma unroll 16
        for (int k = 0; k < DEC; k++) s += wdp[(size_t)k * ATTN] * hs[k];
        wdec[(size_t)b * ATTN + t] = s + b_dec[t];
    }
}

extern "C" void kernel_launch(void* const* d_in, const int* in_sizes, int n_in,
                              void* d_out, int out_size, void* d_ws, size_t ws_size,
                              hipStream_t stream) {
    const float* enc_out = (const float*)d_in[0];
    const float* W_enc   = (const float*)d_in[1];
    const float* b_enc   = (const float*)d_in[2];
    const float* W_dec   = (const float*)d_in[3];
    const float* b_dec   = (const float*)d_in[4];
    const float* v_e     = (const float*)d_in[5];
    const float* b_e     = (const float*)d_in[6];
    const float* emb     = (const float*)d_in[7];
    const float* W_ih    = (const float*)d_in[8];
    const float* W_hh    = (const float*)d_in[9];
    const float* b_ih    = (const float*)d_in[10];
    const float* b_hh    = (const float*)d_in[11];
    const float* W_out   = (const float*)d_in[12];
    const float* b_out   = (const float*)d_in[13];

    float* ws    = (float*)d_ws;
    float* weT   = ws + OFF_WET;
    float* Wgr   = ws + OFF_WGR;
    float* bgr   = ws + OFF_BGR;
    float* WoutT = ws + OFF_WOUTT;
    float* WdT   = ws + OFF_WDT;
    float* c     = ws + OFF_C;
    float* wdec  = ws + OFF_WDEC;
    float* Xcat  = ws + OFF_XCAT;
    float* gpart = ws + OFF_GPART;

    float* logp_out  = (float*)d_out;
    float* preds_out = logp_out + (size_t)BS * TMAX * VOCAB;
    float* attn_out  = preds_out + (size_t)BS * TMAX;

    {
        long n = (long)G4 * KCAT + G4 + (long)DEC * VOCAB + (long)DEC * ATTN;
        k_prep<<<(int)((n + 255) / 256), 256, 0, stream>>>(W_ih, W_hh, b_ih, b_hh, W_out, W_dec,
                                                           Wgr, bgr, WoutT, WdT);
    }
    {
        long n = (long)BS * DEC + (long)BS * KCAT + (long)BS * ATTN;
        k_init<<<(int)((n + 255) / 256), 256, 0, stream>>>(emb, b_dec, c, Xcat, wdec);
    }
    k_wenc<<<dim3(8, 8, 128), 256, 0, stream>>>(W_enc, b_enc, enc_out, weT);

    for (int t = 0; t < TMAX; t++) {
        k_attn<<<128, 512, 0, stream>>>(weT, wdec, v_e, b_e, enc_out, attn_out, Xcat, t);
        k_gates<<<dim3(64, 2, 4), 256, 0, stream>>>(Wgr, Xcat, gpart);
        k_out_cell<<<128, 512, 0, stream>>>(gpart, bgr, WoutT, b_out, emb, WdT, b_dec,
                                            c, logp_out, preds_out, Xcat, wdec, t);
    }
}